// Round 9
// baseline (166.712 us; speedup 1.0000x reference)
//
#include <hip/hip_runtime.h>
#include <hip/hip_bf16.h>
#include <math.h>
#include <stdint.h>

using bf16 = __hip_bfloat16;
typedef __attribute__((ext_vector_type(8))) short short8;
typedef __attribute__((ext_vector_type(4))) short short4v;
typedef __attribute__((ext_vector_type(4))) float float4v;

#define MFMA16(a, b, c) __builtin_amdgcn_mfma_f32_16x16x32_bf16(a, b, c, 0, 0, 0)

__device__ __forceinline__ short bfbits(float f) {
  bf16 h = (bf16)f;
  return *(short*)&h;
}

__device__ __forceinline__ short8 ld_cvt8(const float* p) {
  union { float4v v[2]; float f[8]; } u;
  u.v[0] = *(const float4v*)p;
  u.v[1] = *(const float4v*)(p + 4);
  short8 r;
#pragma unroll
  for (int j = 0; j < 8; j++) r[j] = bfbits(u.f[j]);
  return r;
}

// global -> LDS direct copy, 16B per lane. LDS dest = uniform base + lane*16.
__device__ __forceinline__ void gload16(const bf16* g, bf16* l) {
  __builtin_amdgcn_global_load_lds(
      (const __attribute__((address_space(1))) void*)g,
      (__attribute__((address_space(3))) void*)l, 16, 0, 0);
}

// ---------------------------------------------------------------------------
// One-shot fp32 -> bf16 conversion of x and the 4 weights.
// ---------------------------------------------------------------------------
__global__ __launch_bounds__(256) void conv_all(
    const float* __restrict__ x, const float* __restrict__ w0,
    const float* __restrict__ w1, const float* __restrict__ w2,
    const float* __restrict__ w3, bf16* __restrict__ cx,
    bf16* __restrict__ cw) {
  size_t gid = ((size_t)blockIdx.x * 256 + threadIdx.x) * 8;
  const float* src;
  bf16* dst;
  size_t off;
  if (gid < 4194304) {
    src = x; dst = cx; off = gid;
  } else {
    size_t r = gid - 4194304;
    int wi = (int)(r >> 18);
    src = wi == 0 ? w0 : wi == 1 ? w1 : wi == 2 ? w2 : w3;
    dst = cw + ((size_t)wi << 18);
    off = r & 262143;
  }
  *(short8*)(dst + off) = ld_cvt8(src + off);
}

// ---------------------------------------------------------------------------
// GEMM (NT, all-bf16): C[MTx128] tile of A[M,512] * W[N,512]^T.
// global_load_lds width=16 staging, both-sides XOR swizzle, BK=64.
// ---------------------------------------------------------------------------
template <int MODE, int MT>
__device__ __forceinline__ void gemm_body(bf16* As, bf16* Bs,
                                          const bf16* __restrict__ A,
                                          const bf16* __restrict__ W,
                                          void* __restrict__ outp,
                                          float oscale) {
  constexpr int MI = MT / 32;
  const int bm = blockIdx.x * MT, bn = blockIdx.y * 128;
  const int tid = threadIdx.x;
  const int lane = tid & 63;
  const int wave = tid >> 6;
  const int lr = lane & 15, quad = lane >> 4;
  const int wm = (wave & 1) * (MT / 2), wn = (wave >> 1) * 64;

  const int srow = lane >> 3;
  const int scl = (lane & 7) ^ (srow & 7);
  const int rsw = lr & 7;

  float4v acc[MI][4] = {};

  for (int k0 = 0; k0 < 512; k0 += 64) {
    __syncthreads();  // previous sub-step's LDS reads complete
#pragma unroll
    for (int j = 0; j < MT / 32; j++) {
      const int m = wave + 4 * j;
      gload16(&A[(size_t)(bm + 8 * m + srow) * 512 + k0 + scl * 8],
              &As[(8 * m) * 64]);
    }
#pragma unroll
    for (int j = 0; j < 4; j++) {
      const int m = wave + 4 * j;
      gload16(&W[(size_t)(bn + 8 * m + srow) * 512 + k0 + scl * 8],
              &Bs[(8 * m) * 64]);
    }
    __syncthreads();  // barrier drains vmcnt: staged tile visible
#pragma unroll
    for (int kk = 0; kk < 2; kk++) {
      short8 af[MI], bfv[4];
#pragma unroll
      for (int i = 0; i < MI; i++)
        af[i] = *(const short8*)
            &As[(wm + i * 16 + lr) * 64 + ((4 * kk + quad) ^ rsw) * 8];
#pragma unroll
      for (int i = 0; i < 4; i++)
        bfv[i] = *(const short8*)
            &Bs[(wn + i * 16 + lr) * 64 + ((4 * kk + quad) ^ rsw) * 8];
#pragma unroll
      for (int mi = 0; mi < MI; mi++)
#pragma unroll
        for (int ni = 0; ni < 4; ni++)
          acc[mi][ni] = MFMA16(af[mi], bfv[ni], acc[mi][ni]);
    }
  }

  const int row0 = bm + wm + quad * 4;
  const int col0 = bn + wn + lr;
#pragma unroll
  for (int mi = 0; mi < MI; mi++) {
#pragma unroll
    for (int ni = 0; ni < 4; ni++) {
      const int col = col0 + ni * 16;
      if (MODE == 1) {
        float* out = (float*)outp;
#pragma unroll
        for (int i = 0; i < 4; i++) {
          int m = row0 + mi * 16 + i;
          out[(size_t)m * 512 + col] = acc[mi][ni][i];
        }
      } else if (MODE == 0) {
        bf16* out = (bf16*)outp;
        const int hh = col >> 6, d = col & 63;
#pragma unroll
        for (int i = 0; i < 4; i++) {
          int m = row0 + mi * 16 + i;
          int bb = m >> 12, t = m & 4095;
          out[(((size_t)(bb * 8 + hh) * 4096 + t) << 6) + d] =
              (bf16)(acc[mi][ni][i] * oscale);
        }
      } else {
        bf16* out = (bf16*)outp;
        const int hh = col >> 6, d = col & 63;
        int m0 = row0 + mi * 16;
        int bb = m0 >> 12, t0 = m0 & 4095;
        short4v pk;
#pragma unroll
        for (int i = 0; i < 4; i++) pk[i] = bfbits(acc[mi][ni][i]);
        *(short4v*)&out[(((size_t)(bb * 8 + hh) * 64 + d) << 12) + t0] = pk;
      }
    }
  }
}

// 0.125 * log2(e): folded into Q so attention scores are in exp2 domain.
#define QSCALE 0.18033688f

__global__ __launch_bounds__(256) void qkv_kernel(
    const bf16* __restrict__ cx, const bf16* __restrict__ cW,
    bf16* q, bf16* k, bf16* vt) {
  __shared__ __align__(16) bf16 As[128 * 64];
  __shared__ __align__(16) bf16 Bs[128 * 64];
  if (blockIdx.z == 0)      gemm_body<0, 128>(As, Bs, cx, cW, q, QSCALE);
  else if (blockIdx.z == 1) gemm_body<0, 128>(As, Bs, cx, cW + 262144, k, 1.0f);
  else                      gemm_body<2, 128>(As, Bs, cx, cW + 2 * 262144, vt, 1.0f);
}

__global__ __launch_bounds__(256) void proj_kernel(
    const bf16* __restrict__ y, const bf16* __restrict__ cWout,
    float* __restrict__ out) {
  __shared__ __align__(16) bf16 As[64 * 64];
  __shared__ __align__(16) bf16 Bs[128 * 64];
  gemm_body<1, 64>(As, Bs, y, cWout, out, 1.0f);
}

// ---------------------------------------------------------------------------
// Flash attention (causal), max-free exp2 softmax, swizzled LDS, in-register
// P, split-K 2 groups, diagonal pairing (uniform 33/32 steps), ones-MFMA l.
// This revision (latency-hiding, same structure):
//  - K staged via global_load_lds issued at the TOP of each step for the
//    NEXT buffer (lands during compute; barrier drains). K never in VGPRs;
//    deletes 2 gloads + 2 ds_write_b128 + vmcnt coupling per thread-step.
//    K LDS layout == GEMM's pre-swizzled-source pattern (chunk c^(row&7)).
//  - V: depth-2 register prefetch (loads for s+2 issue at s), static A/B
//    register sets via 2-unrolled loop -> vstore's vmcnt wait is on loads
//    issued a full step earlier.
//  - s_setprio(1) around MFMA clusters (2 independent blocks/CU).
// ---------------------------------------------------------------------------
__device__ __forceinline__ int lsw(int row, int col) {
  return (row << 6) + (col ^ ((row & 7) << 3));
}

template <bool DIAG>
__device__ __forceinline__ void attn_step(const bf16* __restrict__ Kc,
                                          const bf16* __restrict__ Vc,
                                          short8 qf0, short8 qf1, short8 ones,
                                          int wave, int lr, int quad,
                                          float4v& Lacc, float4v* O) {
  // QK^T swapped: S^T tile nc covers k-rows [16nc,16nc+16), cols q = lr.
  float4v S[4] = {};
  __builtin_amdgcn_s_setprio(1);
#pragma unroll
  for (int nc = 0; nc < 4; nc++) {
    short8 kf0 = *(const short8*)&Kc[lsw(nc * 16 + lr, quad * 8)];
    short8 kf1 = *(const short8*)&Kc[lsw(nc * 16 + lr, 32 + quad * 8)];
    S[nc] = MFMA16(kf0, qf0, S[nc]);
    S[nc] = MFMA16(kf1, qf1, S[nc]);
  }
  __builtin_amdgcn_s_setprio(0);

  // softmax (exp2 domain) + in-lane P pack (P[q=lr][k'=16nc+4quad+i]).
  short8 pf0, pf1;
#pragma unroll
  for (int nc = 0; nc < 4; nc++) {
#pragma unroll
    for (int i = 0; i < 4; i++) {
      float pv = exp2f(S[nc][i]);
      if (DIAG) {
        int kl = nc * 16 + quad * 4 + i;
        pv = (kl > wave * 16 + lr) ? 0.f : pv;
      }
      short bb = bfbits(pv);
      if (nc == 0)      pf0[i] = bb;
      else if (nc == 1) pf0[4 + i] = bb;
      else if (nc == 2) pf1[i] = bb;
      else              pf1[4 + i] = bb;
    }
  }

  __builtin_amdgcn_s_setprio(1);
  // l row-sums on the MFMA pipe: Lacc[i] = l[q = wave*16 + quad*4 + i].
  Lacc = MFMA16(pf0, ones, Lacc);
  Lacc = MFMA16(pf1, ones, Lacc);

  // PV: V pre-permuted in LDS -> straight swizzled b128 reads.
#pragma unroll
  for (int nc = 0; nc < 4; nc++) {
    const int row = nc * 16 + lr;
    short8 vfa = *(const short8*)&Vc[lsw(row, quad * 8)];
    short8 vfb = *(const short8*)&Vc[lsw(row, 32 + quad * 8)];
    O[nc] = MFMA16(pf0, vfa, O[nc]);
    O[nc] = MFMA16(pf1, vfb, O[nc]);
  }
  __builtin_amdgcn_s_setprio(0);
}

// permuted V staging: global cols [8s, 8s+8) of a row land in LDS columns
// {vA..vA+3, vA+8..vA+11} where vA = 32*(s>>2) + 16*(s&1) + 4*((s>>1)&1).
__device__ __forceinline__ void vstore_perm(bf16* Vb, int row, int vA,
                                            short8 rv) {
  short4v lo = __builtin_shufflevector(rv, rv, 0, 1, 2, 3);
  short4v hi = __builtin_shufflevector(rv, rv, 4, 5, 6, 7);
  *(short4v*)&Vb[lsw(row, vA)] = lo;
  *(short4v*)&Vb[lsw(row, vA + 8)] = hi;
}

__global__ __launch_bounds__(512, 4) void attn_kernel(const bf16* __restrict__ Qg,
                                                      const bf16* __restrict__ Kg,
                                                      const bf16* __restrict__ Vtg,
                                                      bf16* __restrict__ Y) {
  constexpr int T = 4096;
  // [group][dbuf][K=0/V=1][64*64] = 64 KB
  __shared__ __align__(16) bf16 KV[2][2][2][64 * 64];

  const int bx = blockIdx.x;           // 0..511
  const int p = bx >> 4;               // pair index: q-tiles p and 63-p
  const int pB = 63 - p;
  const int hb = bx & 15;
  const int h = hb >> 1, b = hb & 1;
  const size_t ho = ((size_t)(b * 8 + h)) * T * 64;
  const bf16* Qh = Qg + ho;
  const bf16* Kh = Kg + ho;
  const bf16* Vth = Vtg + ho;

  const int tid = threadIdx.x;
  const int G = tid >> 8;              // split-K group (4 waves each)
  const int t = tid & 255;
  const int wave = t >> 6, lane = t & 63;
  const int lr = lane & 15, quad = lane >> 4;

  // uniform split of the pair's 65 kt-tiles (33 G0 / 32 G1)
  const int hA = (p + 2) >> 1;
  const int hB = (65 - p) >> 1;
  const int myA = G ? (p + 1 - hA) : hA;
  const int aB = G ? hA : 0;
  const int bB = G ? hB : 0;
  const int mysteps = myA + (G ? (64 - p - hB) : hB);

  auto kt_of = [&](int s) { return (s < myA) ? (aB + s) : (bB + (s - myA)); };

  bf16* const Kb0 = KV[G][0][0];
  bf16* const Kb1 = KV[G][1][0];
  bf16* const Vb0 = KV[G][0][1];
  bf16* const Vb1 = KV[G][1][1];

  // K gload geometry: per wave, rows wave*16+8j (j=0,1), lane covers
  // (srowK = lane>>3, chunk lane&7), source chunk pre-swizzled.
  const int srowK = lane >> 3;
  const int sclK = (lane & 7) ^ (srowK & 7);

  // V staging geometry (reg path): rows sr, sr+32, cols sc..sc+7
  const int sr = t >> 3;
  const int s8 = t & 7;
  const int sc = s8 * 8;
  const int vA = 32 * (s8 >> 2) + 16 * (s8 & 1) + 4 * ((s8 >> 1) & 1);
  const bf16* vsrc0 = Vth + (size_t)sr * T + sc;   // + kt*64
  const bf16* vsrc1 = vsrc0 + (size_t)32 * T;

  const int kt0 = kt_of(0), kt1 = kt_of(1);

  // V loads for steps 0 and 1 issued up front (depth-2 from the start)
  short8 rvA0 = *(const short8*)(vsrc0 + (size_t)kt0 * 64);
  short8 rvA1 = *(const short8*)(vsrc1 + (size_t)kt0 * 64);
  short8 rvB0 = *(const short8*)(vsrc0 + (size_t)kt1 * 64);
  short8 rvB1 = *(const short8*)(vsrc1 + (size_t)kt1 * 64);

  // K(step 0) direct to LDS
#pragma unroll
  for (int j = 0; j < 2; j++) {
    const int rb = wave * 16 + 8 * j;
    gload16(&Kh[(size_t)(kt0 * 64 + rb + srowK) * 64 + sclK * 8],
            &Kb0[rb * 64]);
  }

  // Q staging: tile A -> G0's Kb1 region, tile B -> G1's Kb1 region.
  {
    int rr = tid >> 3, c = (tid & 7) * 8;
    *(short8*)&KV[0][1][0][lsw(rr, c)] =
        *(const short8*)&Qh[(size_t)(p * 64 + rr) * 64 + c];
    *(short8*)&KV[1][1][0][lsw(rr, c)] =
        *(const short8*)&Qh[(size_t)(pB * 64 + rr) * 64 + c];
  }
  __syncthreads();  // Q visible + K(0) gload drained
  short8 qfA0 = *(const short8*)&KV[0][1][0][lsw(wave * 16 + lr, quad * 8)];
  short8 qfA1 = *(const short8*)&KV[0][1][0][lsw(wave * 16 + lr, 32 + quad * 8)];
  short8 qfB0 = *(const short8*)&KV[1][1][0][lsw(wave * 16 + lr, quad * 8)];
  short8 qfB1 = *(const short8*)&KV[1][1][0][lsw(wave * 16 + lr, 32 + quad * 8)];
  vstore_perm(Vb0, sr, vA, rvA0);
  vstore_perm(Vb0, sr + 32, vA, rvA1);
  __syncthreads();  // qf reads done + buf 0 fully staged

  short8 ones;
#pragma unroll
  for (int j = 0; j < 8; j++) ones[j] = (short)0x3F80;  // bf16 1.0

  float4v OA[4] = {}, OB[4] = {};
  float4v LA = {}, LB = {};

  // Per step s: gload K(s+1) -> next buf; issue V(s+2) -> VI regs;
  // compute(s); vstore V(s+1) from VW regs (loaded last iter); barrier.
#define ASTEP(S, VI0, VI1, VW0, VW1)                                          \
  {                                                                           \
    const int _s = (S);                                                       \
    if (_s + 1 < mysteps) {                                                   \
      const int ktn = kt_of(_s + 1);                                          \
      bf16* Kn = (_s & 1) ? Kb0 : Kb1;                                        \
      _Pragma("unroll")                                                       \
      for (int j = 0; j < 2; j++) {                                           \
        const int rb = wave * 16 + 8 * j;                                     \
        gload16(&Kh[(size_t)(ktn * 64 + rb + srowK) * 64 + sclK * 8],         \
                &Kn[rb * 64]);                                                \
      }                                                                       \
    }                                                                         \
    if (_s + 2 < mysteps) {                                                   \
      const int ktn = kt_of(_s + 2);                                          \
      VI0 = *(const short8*)(vsrc0 + (size_t)ktn * 64);                       \
      VI1 = *(const short8*)(vsrc1 + (size_t)ktn * 64);                       \
    }                                                                         \
    if (_s < mysteps) {                                                       \
      const bf16* Kc = (_s & 1) ? Kb1 : Kb0;                                  \
      const bf16* Vc = (_s & 1) ? Vb1 : Vb0;                                  \
      if (_s < myA) {                                                         \
        if (aB + _s == p)                                                     \
          attn_step<true>(Kc, Vc, qfA0, qfA1, ones, wave, lr, quad, LA, OA);  \
        else                                                                  \
          attn_step<false>(Kc, Vc, qfA0, qfA1, ones, wave, lr, quad, LA, OA); \
      } else {                                                                \
        if (bB + (_s - myA) == pB)                                            \
          attn_step<true>(Kc, Vc, qfB0, qfB1, ones, wave, lr, quad, LB, OB);  \
        else                                                                  \
          attn_step<false>(Kc, Vc, qfB0, qfB1, ones, wave, lr, quad, LB, OB); \
      }                                                                       \
    }                                                                         \
    if (_s + 1 < mysteps) {                                                   \
      bf16* Vn = (_s & 1) ? Vb0 : Vb1;                                        \
      vstore_perm(Vn, sr, vA, VW0);                                           \
      vstore_perm(Vn, sr + 32, vA, VW1);                                      \
    }                                                                         \
    __syncthreads();                                                          \
  }

  for (int s = 0; s < 32; s += 2) {
    ASTEP(s,     rvA0, rvA1, rvB0, rvB1);
    ASTEP(s + 1, rvB0, rvB1, rvA0, rvA1);
  }
  ASTEP(32, rvA0, rvA1, rvB0, rvB1);
#undef ASTEP

  // ---- split-k combine: G1 dumps partials (both tiles) into LDS ----------
  float* OpA = (float*)&KV[1][0][0][0];  // 16 KB (G1 dbuf0 K+V)
  float* OpB = (float*)&KV[1][1][0][0];  // 16 KB (G1 dbuf1 K+V)
  float* LpA = (float*)&KV[0][0][0][0];  // 64 f32 (G0 region, staging dead)
  float* LpB = LpA + 64;
  const int r0 = wave * 16 + quad * 4;
  if (G == 1) {
#pragma unroll
    for (int nc = 0; nc < 4; nc++)
#pragma unroll
      for (int i = 0; i < 4; i++) {
        OpA[(r0 + i) * 64 + nc * 16 + lr] = OA[nc][i];
        OpB[(r0 + i) * 64 + nc * 16 + lr] = OB[nc][i];
      }
    if (lr == 0) {
#pragma unroll
      for (int i = 0; i < 4; i++) { LpA[r0 + i] = LA[i]; LpB[r0 + i] = LB[i]; }
    }
  }
  __syncthreads();
  if (G == 0) {
    float invA[4], invB[4];
#pragma unroll
    for (int i = 0; i < 4; i++) {
      invA[i] = 1.f / (LA[i] + LpA[r0 + i]);
      invB[i] = 1.f / (LB[i] + LpB[r0 + i]);
    }
    const size_t ybA = ((size_t)b * T + p * 64 + r0) * 512 + h * 64;
    const size_t ybB = ((size_t)b * T + pB * 64 + r0) * 512 + h * 64;
#pragma unroll
    for (int nc = 0; nc < 4; nc++)
#pragma unroll
      for (int i = 0; i < 4; i++) {
        float oa = OA[nc][i] + OpA[(r0 + i) * 64 + nc * 16 + lr];
        float ob = OB[nc][i] + OpB[(r0 + i) * 64 + nc * 16 + lr];
        Y[ybA + (size_t)i * 512 + nc * 16 + lr] = (bf16)(oa * invA[i]);
        Y[ybB + (size_t)i * 512 + nc * 16 + lr] = (bf16)(ob * invB[i]);
      }
  }
}

// ---------------------------------------------------------------------------
extern "C" void kernel_launch(void* const* d_in, const int* in_sizes, int n_in,
                              void* d_out, int out_size, void* d_ws, size_t ws_size,
                              hipStream_t stream) {
  (void)out_size; (void)ws_size;
  // Interface verified R9: dict-order slots, fp32 in, x=[B,T,C], fp32 out.
  const int NX = 8192 * 512;
  int xi = 0;
  for (int i = 0; i < n_in; i++)
    if (in_sizes[i] == NX) { xi = i; break; }
  const float* x = (const float*)d_in[xi];
  const float* wsrc[4];
  int wn = 0;
  for (int i = 0; i < n_in && wn < 4; i++)
    if (i != xi) wsrc[wn++] = (const float*)d_in[i];

  bf16* ws = (bf16*)d_ws;
  const size_t HE = (size_t)NX;
  bf16* q  = ws;                 // 8 MB
  bf16* k  = q + HE;             // 8 MB
  bf16* yx = k + HE;             // 8 MB: bf16 x during qkv, y after attn
  bf16* cw = yx + HE;            // 2 MB (4 weights)  -> 26 MB ws total
  bf16* vt = (bf16*)d_out;       // V^T staged in d_out, consumed before proj
  float* out = (float*)d_out;

  conv_all<<<2560, 256, 0, stream>>>(x, wsrc[0], wsrc[1], wsrc[2], wsrc[3],
                                     yx, cw);
  qkv_kernel<<<dim3(64, 4, 3), 256, 0, stream>>>(yx, cw, q, k, vt);
  attn_kernel<<<512, 512, 0, stream>>>(q, k, vt, yx);
  proj_kernel<<<dim3(128, 4), 256, 0, stream>>>(yx, cw + 3 * 262144, out);
}

// Round 10
// 166.595 us; speedup vs baseline: 1.0007x; 1.0007x over previous
//
#include <hip/hip_runtime.h>
#include <hip/hip_bf16.h>
#include <math.h>
#include <stdint.h>

using bf16 = __hip_bfloat16;
typedef __attribute__((ext_vector_type(8))) short short8;
typedef __attribute__((ext_vector_type(4))) short short4v;
typedef __attribute__((ext_vector_type(4))) float float4v;

#define MFMA16(a, b, c) __builtin_amdgcn_mfma_f32_16x16x32_bf16(a, b, c, 0, 0, 0)

__device__ __forceinline__ short bfbits(float f) {
  bf16 h = (bf16)f;
  return *(short*)&h;
}

__device__ __forceinline__ short8 ld_cvt8(const float* p) {
  union { float4v v[2]; float f[8]; } u;
  u.v[0] = *(const float4v*)p;
  u.v[1] = *(const float4v*)(p + 4);
  short8 r;
#pragma unroll
  for (int j = 0; j < 8; j++) r[j] = bfbits(u.f[j]);
  return r;
}

// global -> LDS direct copy, 16B per lane. LDS dest = uniform base + lane*16.
__device__ __forceinline__ void gload16(const bf16* g, bf16* l) {
  __builtin_amdgcn_global_load_lds(
      (const __attribute__((address_space(1))) void*)g,
      (__attribute__((address_space(3))) void*)l, 16, 0, 0);
}

// ---------------------------------------------------------------------------
// One-shot fp32 -> bf16 conversion of x and the 4 weights.
// ---------------------------------------------------------------------------
__global__ __launch_bounds__(256) void conv_all(
    const float* __restrict__ x, const float* __restrict__ w0,
    const float* __restrict__ w1, const float* __restrict__ w2,
    const float* __restrict__ w3, bf16* __restrict__ cx,
    bf16* __restrict__ cw) {
  size_t gid = ((size_t)blockIdx.x * 256 + threadIdx.x) * 8;
  const float* src;
  bf16* dst;
  size_t off;
  if (gid < 4194304) {
    src = x; dst = cx; off = gid;
  } else {
    size_t r = gid - 4194304;
    int wi = (int)(r >> 18);
    src = wi == 0 ? w0 : wi == 1 ? w1 : wi == 2 ? w2 : w3;
    dst = cw + ((size_t)wi << 18);
    off = r & 262143;
  }
  *(short8*)(dst + off) = ld_cvt8(src + off);
}

// ---------------------------------------------------------------------------
// GEMM (NT, all-bf16): C[MTx128] tile of A[M,512] * W[N,512]^T.
// This revision: SOFTWARE-PIPELINED k-steps with double-buffered LDS.
// Per step s: issue gload_lds for step s+1 into buf[(s+1)&1]; compute step s
// from buf[s&1]; __syncthreads (its implicit vmcnt(0) drains loads issued a
// full compute-phase earlier). ONE barrier per step (was 2), and the drain
// overlaps ~350 cyc of MFMA+ds_read instead of stalling the full HBM
// latency. Race-free: buf[(s+1)&1]'s last readers finished before the
// step-(s-1) barrier, which all waves crossed before any issues step s+1.
// Both-sides XOR swizzle (pre-swizzled global source chunk + swizzled
// ds_read_b128) unchanged. BK=64, 8 k-steps.
// MODE 0: out[b,h,t,d] bf16 scaled (Q,K). MODE 1: out[m,n] fp32 (proj).
// MODE 2: out[b,h,d,t] bf16 (V^T).
// ---------------------------------------------------------------------------
template <int MODE, int MT>
__device__ __forceinline__ void gemm_body(bf16* As, bf16* Bs,
                                          const bf16* __restrict__ A,
                                          const bf16* __restrict__ W,
                                          void* __restrict__ outp,
                                          float oscale) {
  constexpr int MI = MT / 32;
  constexpr int ASZ = MT * 64;
  constexpr int BSZ = 128 * 64;
  const int bm = blockIdx.x * MT, bn = blockIdx.y * 128;
  const int tid = threadIdx.x;
  const int lane = tid & 63;
  const int wave = tid >> 6;
  const int lr = lane & 15, quad = lane >> 4;
  const int wm = (wave & 1) * (MT / 2), wn = (wave >> 1) * 64;

  const int srow = lane >> 3;
  const int scl = (lane & 7) ^ (srow & 7);
  const int rsw = lr & 7;

  float4v acc[MI][4] = {};

  // stage k-step (k0) into buffer b
  auto stage = [&](int k0, int b) {
    bf16* Ad = As + b * ASZ;
    bf16* Bd = Bs + b * BSZ;
#pragma unroll
    for (int j = 0; j < MT / 32; j++) {
      const int m = wave + 4 * j;
      gload16(&A[(size_t)(bm + 8 * m + srow) * 512 + k0 + scl * 8],
              &Ad[(8 * m) * 64]);
    }
#pragma unroll
    for (int j = 0; j < 4; j++) {
      const int m = wave + 4 * j;
      gload16(&W[(size_t)(bn + 8 * m + srow) * 512 + k0 + scl * 8],
              &Bd[(8 * m) * 64]);
    }
  };

  stage(0, 0);
  __syncthreads();  // buf0 staged (one-time pipeline fill)

  for (int s = 0; s < 8; s++) {
    if (s + 1 < 8) stage(64 * (s + 1), (s + 1) & 1);  // overlaps compute below
    const bf16* Ac = As + (s & 1) * ASZ;
    const bf16* Bc = Bs + (s & 1) * BSZ;
#pragma unroll
    for (int kk = 0; kk < 2; kk++) {
      short8 af[MI], bfv[4];
#pragma unroll
      for (int i = 0; i < MI; i++)
        af[i] = *(const short8*)
            &Ac[(wm + i * 16 + lr) * 64 + ((4 * kk + quad) ^ rsw) * 8];
#pragma unroll
      for (int i = 0; i < 4; i++)
        bfv[i] = *(const short8*)
            &Bc[(wn + i * 16 + lr) * 64 + ((4 * kk + quad) ^ rsw) * 8];
#pragma unroll
      for (int mi = 0; mi < MI; mi++)
#pragma unroll
        for (int ni = 0; ni < 4; ni++)
          acc[mi][ni] = MFMA16(af[mi], bfv[ni], acc[mi][ni]);
    }
    __syncthreads();  // single barrier per step: drains s+1 loads, frees buf
  }

  const int row0 = bm + wm + quad * 4;
  const int col0 = bn + wn + lr;
#pragma unroll
  for (int mi = 0; mi < MI; mi++) {
#pragma unroll
    for (int ni = 0; ni < 4; ni++) {
      const int col = col0 + ni * 16;
      if (MODE == 1) {
        float* out = (float*)outp;
#pragma unroll
        for (int i = 0; i < 4; i++) {
          int m = row0 + mi * 16 + i;
          out[(size_t)m * 512 + col] = acc[mi][ni][i];
        }
      } else if (MODE == 0) {
        bf16* out = (bf16*)outp;
        const int hh = col >> 6, d = col & 63;
#pragma unroll
        for (int i = 0; i < 4; i++) {
          int m = row0 + mi * 16 + i;
          int bb = m >> 12, t = m & 4095;
          out[(((size_t)(bb * 8 + hh) * 4096 + t) << 6) + d] =
              (bf16)(acc[mi][ni][i] * oscale);
        }
      } else {
        bf16* out = (bf16*)outp;
        const int hh = col >> 6, d = col & 63;
        int m0 = row0 + mi * 16;
        int bb = m0 >> 12, t0 = m0 & 4095;
        short4v pk;
#pragma unroll
        for (int i = 0; i < 4; i++) pk[i] = bfbits(acc[mi][ni][i]);
        *(short4v*)&out[(((size_t)(bb * 8 + hh) * 64 + d) << 12) + t0] = pk;
      }
    }
  }
}

// 0.125 * log2(e): folded into Q so attention scores are in exp2 domain.
#define QSCALE 0.18033688f

__global__ __launch_bounds__(256) void qkv_kernel(
    const bf16* __restrict__ cx, const bf16* __restrict__ cW,
    bf16* q, bf16* k, bf16* vt) {
  __shared__ __align__(16) bf16 As[2 * 128 * 64];  // dbuf: 32 KB
  __shared__ __align__(16) bf16 Bs[2 * 128 * 64];  // dbuf: 32 KB
  if (blockIdx.z == 0)      gemm_body<0, 128>(As, Bs, cx, cW, q, QSCALE);
  else if (blockIdx.z == 1) gemm_body<0, 128>(As, Bs, cx, cW + 262144, k, 1.0f);
  else                      gemm_body<2, 128>(As, Bs, cx, cW + 2 * 262144, vt, 1.0f);
}

__global__ __launch_bounds__(256) void proj_kernel(
    const bf16* __restrict__ y, const bf16* __restrict__ cWout,
    float* __restrict__ out) {
  __shared__ __align__(16) bf16 As[2 * 64 * 64];   // dbuf: 16 KB
  __shared__ __align__(16) bf16 Bs[2 * 128 * 64];  // dbuf: 32 KB
  gemm_body<1, 64>(As, Bs, y, cWout, out, 1.0f);
}

// ---------------------------------------------------------------------------
// Flash attention (causal) — UNCHANGED from R9 for attribution.
// Max-free exp2 softmax, swizzled LDS, in-register P, split-K 2 groups,
// diagonal pairing (uniform 33/32 steps), ones-MFMA l, K via global_load_lds,
// depth-2 V register prefetch, setprio around MFMA clusters.
// ---------------------------------------------------------------------------
__device__ __forceinline__ int lsw(int row, int col) {
  return (row << 6) + (col ^ ((row & 7) << 3));
}

template <bool DIAG>
__device__ __forceinline__ void attn_step(const bf16* __restrict__ Kc,
                                          const bf16* __restrict__ Vc,
                                          short8 qf0, short8 qf1, short8 ones,
                                          int wave, int lr, int quad,
                                          float4v& Lacc, float4v* O) {
  // QK^T swapped: S^T tile nc covers k-rows [16nc,16nc+16), cols q = lr.
  float4v S[4] = {};
  __builtin_amdgcn_s_setprio(1);
#pragma unroll
  for (int nc = 0; nc < 4; nc++) {
    short8 kf0 = *(const short8*)&Kc[lsw(nc * 16 + lr, quad * 8)];
    short8 kf1 = *(const short8*)&Kc[lsw(nc * 16 + lr, 32 + quad * 8)];
    S[nc] = MFMA16(kf0, qf0, S[nc]);
    S[nc] = MFMA16(kf1, qf1, S[nc]);
  }
  __builtin_amdgcn_s_setprio(0);

  // softmax (exp2 domain) + in-lane P pack (P[q=lr][k'=16nc+4quad+i]).
  short8 pf0, pf1;
#pragma unroll
  for (int nc = 0; nc < 4; nc++) {
#pragma unroll
    for (int i = 0; i < 4; i++) {
      float pv = exp2f(S[nc][i]);
      if (DIAG) {
        int kl = nc * 16 + quad * 4 + i;
        pv = (kl > wave * 16 + lr) ? 0.f : pv;
      }
      short bb = bfbits(pv);
      if (nc == 0)      pf0[i] = bb;
      else if (nc == 1) pf0[4 + i] = bb;
      else if (nc == 2) pf1[i] = bb;
      else              pf1[4 + i] = bb;
    }
  }

  __builtin_amdgcn_s_setprio(1);
  // l row-sums on the MFMA pipe: Lacc[i] = l[q = wave*16 + quad*4 + i].
  Lacc = MFMA16(pf0, ones, Lacc);
  Lacc = MFMA16(pf1, ones, Lacc);

  // PV: V pre-permuted in LDS -> straight swizzled b128 reads.
#pragma unroll
  for (int nc = 0; nc < 4; nc++) {
    const int row = nc * 16 + lr;
    short8 vfa = *(const short8*)&Vc[lsw(row, quad * 8)];
    short8 vfb = *(const short8*)&Vc[lsw(row, 32 + quad * 8)];
    O[nc] = MFMA16(pf0, vfa, O[nc]);
    O[nc] = MFMA16(pf1, vfb, O[nc]);
  }
  __builtin_amdgcn_s_setprio(0);
}

// permuted V staging: global cols [8s, 8s+8) of a row land in LDS columns
// {vA..vA+3, vA+8..vA+11} where vA = 32*(s>>2) + 16*(s&1) + 4*((s>>1)&1).
__device__ __forceinline__ void vstore_perm(bf16* Vb, int row, int vA,
                                            short8 rv) {
  short4v lo = __builtin_shufflevector(rv, rv, 0, 1, 2, 3);
  short4v hi = __builtin_shufflevector(rv, rv, 4, 5, 6, 7);
  *(short4v*)&Vb[lsw(row, vA)] = lo;
  *(short4v*)&Vb[lsw(row, vA + 8)] = hi;
}

__global__ __launch_bounds__(512, 4) void attn_kernel(const bf16* __restrict__ Qg,
                                                      const bf16* __restrict__ Kg,
                                                      const bf16* __restrict__ Vtg,
                                                      bf16* __restrict__ Y) {
  constexpr int T = 4096;
  // [group][dbuf][K=0/V=1][64*64] = 64 KB
  __shared__ __align__(16) bf16 KV[2][2][2][64 * 64];

  const int bx = blockIdx.x;           // 0..511
  const int p = bx >> 4;               // pair index: q-tiles p and 63-p
  const int pB = 63 - p;
  const int hb = bx & 15;
  const int h = hb >> 1, b = hb & 1;
  const size_t ho = ((size_t)(b * 8 + h)) * T * 64;
  const bf16* Qh = Qg + ho;
  const bf16* Kh = Kg + ho;
  const bf16* Vth = Vtg + ho;

  const int tid = threadIdx.x;
  const int G = tid >> 8;              // split-K group (4 waves each)
  const int t = tid & 255;
  const int wave = t >> 6, lane = t & 63;
  const int lr = lane & 15, quad = lane >> 4;

  // uniform split of the pair's 65 kt-tiles (33 G0 / 32 G1)
  const int hA = (p + 2) >> 1;
  const int hB = (65 - p) >> 1;
  const int myA = G ? (p + 1 - hA) : hA;
  const int aB = G ? hA : 0;
  const int bB = G ? hB : 0;
  const int mysteps = myA + (G ? (64 - p - hB) : hB);

  auto kt_of = [&](int s) { return (s < myA) ? (aB + s) : (bB + (s - myA)); };

  bf16* const Kb0 = KV[G][0][0];
  bf16* const Kb1 = KV[G][1][0];
  bf16* const Vb0 = KV[G][0][1];
  bf16* const Vb1 = KV[G][1][1];

  // K gload geometry: per wave, rows wave*16+8j (j=0,1), lane covers
  // (srowK = lane>>3, chunk lane&7), source chunk pre-swizzled.
  const int srowK = lane >> 3;
  const int sclK = (lane & 7) ^ (srowK & 7);

  // V staging geometry (reg path): rows sr, sr+32, cols sc..sc+7
  const int sr = t >> 3;
  const int s8 = t & 7;
  const int sc = s8 * 8;
  const int vA = 32 * (s8 >> 2) + 16 * (s8 & 1) + 4 * ((s8 >> 1) & 1);
  const bf16* vsrc0 = Vth + (size_t)sr * T + sc;   // + kt*64
  const bf16* vsrc1 = vsrc0 + (size_t)32 * T;

  const int kt0 = kt_of(0), kt1 = kt_of(1);

  // V loads for steps 0 and 1 issued up front (depth-2 from the start)
  short8 rvA0 = *(const short8*)(vsrc0 + (size_t)kt0 * 64);
  short8 rvA1 = *(const short8*)(vsrc1 + (size_t)kt0 * 64);
  short8 rvB0 = *(const short8*)(vsrc0 + (size_t)kt1 * 64);
  short8 rvB1 = *(const short8*)(vsrc1 + (size_t)kt1 * 64);

  // K(step 0) direct to LDS
#pragma unroll
  for (int j = 0; j < 2; j++) {
    const int rb = wave * 16 + 8 * j;
    gload16(&Kh[(size_t)(kt0 * 64 + rb + srowK) * 64 + sclK * 8],
            &Kb0[rb * 64]);
  }

  // Q staging: tile A -> G0's Kb1 region, tile B -> G1's Kb1 region.
  {
    int rr = tid >> 3, c = (tid & 7) * 8;
    *(short8*)&KV[0][1][0][lsw(rr, c)] =
        *(const short8*)&Qh[(size_t)(p * 64 + rr) * 64 + c];
    *(short8*)&KV[1][1][0][lsw(rr, c)] =
        *(const short8*)&Qh[(size_t)(pB * 64 + rr) * 64 + c];
  }
  __syncthreads();  // Q visible + K(0) gload drained
  short8 qfA0 = *(const short8*)&KV[0][1][0][lsw(wave * 16 + lr, quad * 8)];
  short8 qfA1 = *(const short8*)&KV[0][1][0][lsw(wave * 16 + lr, 32 + quad * 8)];
  short8 qfB0 = *(const short8*)&KV[1][1][0][lsw(wave * 16 + lr, quad * 8)];
  short8 qfB1 = *(const short8*)&KV[1][1][0][lsw(wave * 16 + lr, 32 + quad * 8)];
  vstore_perm(Vb0, sr, vA, rvA0);
  vstore_perm(Vb0, sr + 32, vA, rvA1);
  __syncthreads();  // qf reads done + buf 0 fully staged

  short8 ones;
#pragma unroll
  for (int j = 0; j < 8; j++) ones[j] = (short)0x3F80;  // bf16 1.0

  float4v OA[4] = {}, OB[4] = {};
  float4v LA = {}, LB = {};

  // Per step s: gload K(s+1) -> next buf; issue V(s+2) -> VI regs;
  // compute(s); vstore V(s+1) from VW regs (loaded last iter); barrier.
#define ASTEP(S, VI0, VI1, VW0, VW1)                                          \
  {                                                                           \
    const int _s = (S);                                                       \
    if (_s + 1 < mysteps) {                                                   \
      const int ktn = kt_of(_s + 1);                                          \
      bf16* Kn = (_s & 1) ? Kb0 : Kb1;                                        \
      _Pragma("unroll")                                                       \
      for (int j = 0; j < 2; j++) {                                           \
        const int rb = wave * 16 + 8 * j;                                     \
        gload16(&Kh[(size_t)(ktn * 64 + rb + srowK) * 64 + sclK * 8],         \
                &Kn[rb * 64]);                                                \
      }                                                                       \
    }                                                                         \
    if (_s + 2 < mysteps) {                                                   \
      const int ktn = kt_of(_s + 2);                                          \
      VI0 = *(const short8*)(vsrc0 + (size_t)ktn * 64);                       \
      VI1 = *(const short8*)(vsrc1 + (size_t)ktn * 64);                       \
    }                                                                         \
    if (_s < mysteps) {                                                       \
      const bf16* Kc = (_s & 1) ? Kb1 : Kb0;                                  \
      const bf16* Vc = (_s & 1) ? Vb1 : Vb0;                                  \
      if (_s < myA) {                                                         \
        if (aB + _s == p)                                                     \
          attn_step<true>(Kc, Vc, qfA0, qfA1, ones, wave, lr, quad, LA, OA);  \
        else                                                                  \
          attn_step<false>(Kc, Vc, qfA0, qfA1, ones, wave, lr, quad, LA, OA); \
      } else {                                                                \
        if (bB + (_s - myA) == pB)                                            \
          attn_step<true>(Kc, Vc, qfB0, qfB1, ones, wave, lr, quad, LB, OB);  \
        else                                                                  \
          attn_step<false>(Kc, Vc, qfB0, qfB1, ones, wave, lr, quad, LB, OB); \
      }                                                                       \
    }                                                                         \
    if (_s + 1 < mysteps) {                                                   \
      bf16* Vn = (_s & 1) ? Vb0 : Vb1;                                        \
      vstore_perm(Vn, sr, vA, VW0);                                           \
      vstore_perm(Vn, sr + 32, vA, VW1);                                      \
    }                                                                         \
    __syncthreads();                                                          \
  }

  for (int s = 0; s < 32; s += 2) {
    ASTEP(s,     rvA0, rvA1, rvB0, rvB1);
    ASTEP(s + 1, rvB0, rvB1, rvA0, rvA1);
  }
  ASTEP(32, rvA0, rvA1, rvB0, rvB1);
#undef ASTEP

  // ---- split-k combine: G1 dumps partials (both tiles) into LDS ----------
  float* OpA = (float*)&KV[1][0][0][0];  // 16 KB (G1 dbuf0 K+V)
  float* OpB = (float*)&KV[1][1][0][0];  // 16 KB (G1 dbuf1 K+V)
  float* LpA = (float*)&KV[0][0][0][0];  // 64 f32 (G0 region, staging dead)
  float* LpB = LpA + 64;
  const int r0 = wave * 16 + quad * 4;
  if (G == 1) {
#pragma unroll
    for (int nc = 0; nc < 4; nc++)
#pragma unroll
      for (int i = 0; i < 4; i++) {
        OpA[(r0 + i) * 64 + nc * 16 + lr] = OA[nc][i];
        OpB[(r0 + i) * 64 + nc * 16 + lr] = OB[nc][i];
      }
    if (lr == 0) {
#pragma unroll
      for (int i = 0; i < 4; i++) { LpA[r0 + i] = LA[i]; LpB[r0 + i] = LB[i]; }
    }
  }
  __syncthreads();
  if (G == 0) {
    float invA[4], invB[4];
#pragma unroll
    for (int i = 0; i < 4; i++) {
      invA[i] = 1.f / (LA[i] + LpA[r0 + i]);
      invB[i] = 1.f / (LB[i] + LpB[r0 + i]);
    }
    const size_t ybA = ((size_t)b * T + p * 64 + r0) * 512 + h * 64;
    const size_t ybB = ((size_t)b * T + pB * 64 + r0) * 512 + h * 64;
#pragma unroll
    for (int nc = 0; nc < 4; nc++)
#pragma unroll
      for (int i = 0; i < 4; i++) {
        float oa = OA[nc][i] + OpA[(r0 + i) * 64 + nc * 16 + lr];
        float ob = OB[nc][i] + OpB[(r0 + i) * 64 + nc * 16 + lr];
        Y[ybA + (size_t)i * 512 + nc * 16 + lr] = (bf16)(oa * invA[i]);
        Y[ybB + (size_t)i * 512 + nc * 16 + lr] = (bf16)(ob * invB[i]);
      }
  }
}

// ---------------------------------------------------------------------------
extern "C" void kernel_launch(void* const* d_in, const int* in_sizes, int n_in,
                              void* d_out, int out_size, void* d_ws, size_t ws_size,
                              hipStream_t stream) {
  (void)out_size; (void)ws_size;
  // Interface verified R9: dict-order slots, fp32 in, x=[B,T,C], fp32 out.
  const int NX = 8192 * 512;
  int xi = 0;
  for (int i = 0; i < n_in; i++)
    if (in_sizes[i] == NX) { xi = i; break; }
  const float* x = (const float*)d_in[xi];
  const float* wsrc[4];
  int wn = 0;
  for (int i = 0; i < n_in && wn < 4; i++)
    if (i != xi) wsrc[wn++] = (const float*)d_in[i];

  bf16* ws = (bf16*)d_ws;
  const size_t HE = (size_t)NX;
  bf16* q  = ws;                 // 8 MB
  bf16* k  = q + HE;             // 8 MB
  bf16* yx = k + HE;             // 8 MB: bf16 x during qkv, y after attn
  bf16* cw = yx + HE;            // 2 MB (4 weights)  -> 26 MB ws total
  bf16* vt = (bf16*)d_out;       // V^T staged in d_out, consumed before proj
  float* out = (float*)d_out;

  conv_all<<<2560, 256, 0, stream>>>(x, wsrc[0], wsrc[1], wsrc[2], wsrc[3],
                                     yx, cw);
  qkv_kernel<<<dim3(64, 4, 3), 256, 0, stream>>>(yx, cw, q, k, vt);
  attn_kernel<<<512, 512, 0, stream>>>(q, k, vt, yx);
  proj_kernel<<<dim3(128, 4), 256, 0, stream>>>(yx, cw + 3 * 262144, out);
}